// Round 2
// baseline (321.447 us; speedup 1.0000x reference)
//
#include <hip/hip_runtime.h>
#include <stdint.h>

#define N_ANCH 262144
#define NUM_CLASSES 80
#define DET_DIM 84
#define TOP_K 1000
#define MAX_BOXES 300
#define NMS_THR 0.4f

// ---- workspace layout (bytes) ----
#define OFF_KEYS   0u
#define OFF_HIST1  (N_ANCH * 4u)             // 4096 u32
#define OFF_HIST2  (OFF_HIST1 + 16384u)      // 4096 u32
#define OFF_STATE  (OFF_HIST2 + 16384u)      // 16 u32: 0:d1 1:k1 2:pre24 3:cnt
#define OFF_LIST   (OFF_STATE + 64u)         // 4096 u32 candidate indices
#define OFF_TOPK   (OFF_LIST + 16384u)       // 1024 u32
#define OFF_BOXK   (OFF_TOPK + 4096u)        // 1024 float4
#define OFF_MASK   (OFF_BOXK + 16384u)       // 1024 rows x 16 u64 = 128 KB

// zero hist1 + hist2 + state contiguously
#define ZERO_WORDS ((16384u + 16384u + 64u) / 4u)   // 8208

__global__ __launch_bounds__(1024) void k_init(uint32_t* __restrict__ z) {
    uint32_t tid = blockIdx.x * 1024u + threadIdx.x;
    if (tid < ZERO_WORDS) z[tid] = 0u;
}

// scores = max over 80 classes; key = float bits (scores >= 0 => monotonic)
__global__ __launch_bounds__(256) void k_scores(const float* __restrict__ cls,
                                                uint32_t* __restrict__ keys,
                                                uint32_t* __restrict__ ghist1) {
    __shared__ uint32_t h[4096];
    for (int i = threadIdx.x; i < 4096; i += 256) h[i] = 0u;
    __syncthreads();
    int a = blockIdx.x * 256 + threadIdx.x;   // grid sized to exactly N_ANCH
    const float4* q = (const float4*)(cls + (size_t)a * NUM_CLASSES);
    float m = -1.0f;
#pragma unroll
    for (int t = 0; t < 20; ++t) {
        float4 v = q[t];
        m = fmaxf(m, fmaxf(fmaxf(v.x, v.y), fmaxf(v.z, v.w)));
    }
    uint32_t key = __float_as_uint(m);
    keys[a] = key;
    atomicAdd(&h[key >> 20], 1u);
    __syncthreads();
    for (int i = threadIdx.x; i < 4096; i += 256) {
        uint32_t v = h[i];
        if (v) atomicAdd(&ghist1[i], v);
    }
}

// wave(64-lane) suffix-scan of a histogram: find bin d with S(d+1) < k <= S(d)
// writes d -> out[0], k - S(d+1) -> out[1]  (exactly one lane writes)
__device__ __forceinline__ void wave_scan_hist(const uint32_t* __restrict__ hist,
                                               int nbins, uint32_t k,
                                               uint32_t* __restrict__ out, int lane) {
    int per = nbins >> 6;
    int base = lane * per;
    uint32_t partial = 0;
    for (int b = 0; b < per; ++b) partial += hist[base + b];
    uint32_t si = partial;
#pragma unroll
    for (int off = 1; off < 64; off <<= 1) {
        uint32_t v = __shfl_down(si, off);
        if (lane + off < 64) si += v;
    }
    uint32_t se = si - partial;   // suffix-sum over lanes > this lane's range... (cum from high bins)
    if (se < k && k <= si) {
        uint32_t running = se;
        for (int b = base + per - 1; b >= base; --b) {
            uint32_t hv = hist[b];
            running += hv;
            if (running >= k) {
                out[0] = (uint32_t)b;
                out[1] = k - (running - hv);
                break;
            }
        }
    }
}

// pass 2: every block redoes the (cheap) scan of hist1, then histograms bits[19:8]
__global__ __launch_bounds__(256) void k_pass2(const uint32_t* __restrict__ keys,
                                               const uint32_t* __restrict__ ghist1,
                                               uint32_t* __restrict__ ghist2,
                                               uint32_t* __restrict__ state) {
    __shared__ uint32_t sd[2];
    __shared__ uint32_t h[4096];
    if (threadIdx.x < 64) wave_scan_hist(ghist1, 4096, TOP_K, sd, threadIdx.x);
    for (int i = threadIdx.x; i < 4096; i += 256) h[i] = 0u;
    __syncthreads();
    uint32_t d1 = sd[0], k1 = sd[1];
    if (threadIdx.x == 0 && blockIdx.x == 0) { state[0] = d1; state[1] = k1; }
    int stride = gridDim.x * 256;
    for (int a = blockIdx.x * 256 + threadIdx.x; a < N_ANCH; a += stride) {
        uint32_t key = keys[a];
        if ((key >> 20) == d1) atomicAdd(&h[(key >> 8) & 0xFFFu], 1u);
    }
    __syncthreads();
    for (int i = threadIdx.x; i < 4096; i += 256) {
        uint32_t v = h[i];
        if (v) atomicAdd(&ghist2[i], v);
    }
}

// pass 3: scan hist2 -> pre24; compact ALL indices with (key>>8) >= pre24.
// Exact: any excluded key is strictly smaller in its top 24 bits than every candidate.
__global__ __launch_bounds__(256) void k_pass3c(const uint32_t* __restrict__ keys,
                                                const uint32_t* __restrict__ ghist2,
                                                uint32_t* __restrict__ state,
                                                uint32_t* __restrict__ list) {
    __shared__ uint32_t sd[2];
    if (threadIdx.x < 64) {
        uint32_t k1 = state[1];
        wave_scan_hist(ghist2, 4096, k1, sd, threadIdx.x);
    }
    __syncthreads();
    uint32_t pre24 = (state[0] << 12) | sd[0];
    if (threadIdx.x == 0 && blockIdx.x == 0) state[2] = pre24;
    int stride = gridDim.x * 256;
    for (int a = blockIdx.x * 256 + threadIdx.x; a < N_ANCH; a += stride) {
        uint32_t key = keys[a];
        if ((key >> 8) >= pre24) {
            uint32_t p = atomicAdd(&state[3], 1u);
            if (p < 4096u) list[p] = (uint32_t)a;
        }
    }
}

// single block: bitonic-sort candidates by (key desc, idx asc), emit topk + gather boxes
__global__ __launch_bounds__(1024) void k_sort(const uint32_t* __restrict__ keys,
                                               const uint32_t* __restrict__ state,
                                               const uint32_t* __restrict__ list,
                                               uint32_t* __restrict__ topk,
                                               const float4* __restrict__ boxes,
                                               float4* __restrict__ boxk) {
    __shared__ unsigned long long A[4096];
    int t = threadIdx.x;
    uint32_t cnt = state[3];
    if (cnt > 4096u) cnt = 4096u;          // expected ~1320
    unsigned n2 = 1024; while (n2 < cnt) n2 <<= 1;   // cnt >= 1000 always
    for (unsigned i = (unsigned)t; i < n2; i += 1024) {
        unsigned long long wv = ~0ull;
        if (i < cnt) {
            uint32_t idx = list[i];
            wv = ((unsigned long long)(~keys[idx]) << 32) | (unsigned long long)idx;
        }
        A[i] = wv;
    }
    __syncthreads();
    for (unsigned k = 2; k <= n2; k <<= 1) {
        for (unsigned j = k >> 1; j > 0; j >>= 1) {
            for (unsigned i = (unsigned)t; i < n2; i += 1024) {
                unsigned ixj = i ^ j;
                if (ixj > i) {
                    unsigned long long a = A[i], b = A[ixj];
                    bool up = ((i & k) == 0);
                    if (up ? (a > b) : (a < b)) { A[i] = b; A[ixj] = a; }
                }
            }
            __syncthreads();
        }
    }
    if (t < TOP_K) {
        uint32_t idx = (uint32_t)(A[t] & 0xFFFFFFFFull);
        topk[t] = idx;
        boxk[t] = boxes[idx];
    }
}

// mask[i][w] bit b: box j=64w+b suppressed by box i (iou>thr && j>i); rows >=1000 zeroed.
// 256 blocks x 4 rows; boxes read through L1/L2 (1000 float4 = 16 KB, fits L1).
__global__ __launch_bounds__(256) void k_mask(const float4* __restrict__ boxk,
                                              unsigned long long* __restrict__ mask) {
    int lane = threadIdx.x & 63;
    int wave = threadIdx.x >> 6;
    for (int r = 0; r < 4; ++r) {
        int i = blockIdx.x * 4 + r;
        if (i >= 1000) {
            if (threadIdx.x < 16) mask[(size_t)i * 16 + threadIdx.x] = 0ull;
            continue;
        }
        float4 bi = boxk[i];
        float areai = __fmul_rn(__fsub_rn(bi.z, bi.x), __fsub_rn(bi.w, bi.y));
#pragma unroll
        for (int rr = 0; rr < 4; ++rr) {
            int j = rr * 256 + threadIdx.x;
            bool bit = false;
            if (j < 1000 && j > i) {
                float4 bj = boxk[j];
                float areaj = __fmul_rn(__fsub_rn(bj.z, bj.x), __fsub_rn(bj.w, bj.y));
                float ix1 = fmaxf(bi.x, bj.x);
                float iy1 = fmaxf(bi.y, bj.y);
                float ix2 = fminf(bi.z, bj.z);
                float iy2 = fminf(bi.w, bj.w);
                float iw = fmaxf(__fsub_rn(ix2, ix1), 0.0f);
                float ih = fmaxf(__fsub_rn(iy2, iy1), 0.0f);
                float inter = __fmul_rn(iw, ih);
                float uni = __fsub_rn(__fadd_rn(areai, areaj), inter);
                float den = fmaxf(uni, 1e-8f);
                float iou = inter / den;   // IEEE RN divide, matches jnp
                bit = iou > NMS_THR;
            }
            unsigned long long bal = __ballot(bit);
            if (lane == 0) mask[(size_t)i * 16 + (rr * 4 + wave)] = bal;
        }
    }
}

// fused: single-wave greedy NMS scan over the bitmask, then 4-wave output gather
__global__ __launch_bounds__(256) void k_nms_out(const unsigned long long* __restrict__ mask,
                                                 const uint32_t* __restrict__ topk,
                                                 const float* __restrict__ det,
                                                 float* __restrict__ out) {
    __shared__ uint32_t keptList[384];
    __shared__ uint32_t selS[MAX_BOXES];
    __shared__ uint32_t kcS;
    int lane = threadIdx.x & 63;
    int wave = threadIdx.x >> 6;
    if (wave == 0) {
        uint32_t keptCount = 0;
        for (int c = 0; c < 16; ++c) {
            unsigned long long acc = 0ull;
            for (uint32_t s = (uint32_t)lane; s < keptCount; s += 64u)
                acc |= mask[(size_t)keptList[s] * 16 + c];
#pragma unroll
            for (int off = 1; off < 64; off <<= 1) acc |= __shfl_xor(acc, off);
            unsigned long long supp = acc;
            unsigned long long row = mask[(size_t)(c * 64 + lane) * 16 + c];
            for (int i = 0; i < 64; ++i) {
                unsigned long long ri = __shfl(row, i);
                if (!((supp >> i) & 1ull)) supp |= ri;
            }
            unsigned long long validm = (c == 15) ? ((1ull << 40) - 1ull) : ~0ull;
            unsigned long long kept = (~supp) & validm;
            uint32_t cnt = (uint32_t)__popcll(kept);
            if ((kept >> lane) & 1ull) {
                uint32_t pos = keptCount + (uint32_t)__popcll(kept & ((1ull << lane) - 1ull));
                if (pos < 384u) keptList[pos] = (uint32_t)(c * 64 + lane);
            }
            keptCount += cnt;
            if (keptCount >= MAX_BOXES) break;
        }
        if (keptCount > MAX_BOXES) keptCount = MAX_BOXES;
        for (uint32_t m = (uint32_t)lane; m < MAX_BOXES; m += 64u)
            selS[m] = (m < keptCount) ? topk[keptList[m]] : 0xFFFFFFFFu;
        if (lane == 0) kcS = keptCount;
    }
    __syncthreads();
    (void)kcS;
    // gather 300 x 84 output rows (4 waves x 75 rows)
    for (int m = wave; m < MAX_BOXES; m += 4) {
        uint32_t s = selS[m];
        const float* src = det + (size_t)s * DET_DIM;
        for (int e = lane; e < DET_DIM; e += 64)
            out[m * DET_DIM + e] = (s == 0xFFFFFFFFu) ? 0.0f : src[e];
    }
}

extern "C" void kernel_launch(void* const* d_in, const int* in_sizes, int n_in,
                              void* d_out, int out_size, void* d_ws, size_t ws_size,
                              hipStream_t stream) {
    const float* boxes = (const float*)d_in[0];
    const float* cls   = (const float*)d_in[1];
    const float* det   = (const float*)d_in[2];
    float* out = (float*)d_out;
    char* ws = (char*)d_ws;

    uint32_t* keys = (uint32_t*)(ws + OFF_KEYS);
    uint32_t* h1   = (uint32_t*)(ws + OFF_HIST1);
    uint32_t* h2   = (uint32_t*)(ws + OFF_HIST2);
    uint32_t* st   = (uint32_t*)(ws + OFF_STATE);
    uint32_t* list = (uint32_t*)(ws + OFF_LIST);
    uint32_t* topk = (uint32_t*)(ws + OFF_TOPK);
    float4*   boxk = (float4*)(ws + OFF_BOXK);
    unsigned long long* mask = (unsigned long long*)(ws + OFF_MASK);

    k_init<<<dim3((ZERO_WORDS + 1023) / 1024), dim3(1024), 0, stream>>>(h1);
    k_scores<<<dim3(N_ANCH / 256), dim3(256), 0, stream>>>(cls, keys, h1);
    k_pass2<<<dim3(256), dim3(256), 0, stream>>>(keys, h1, h2, st);
    k_pass3c<<<dim3(256), dim3(256), 0, stream>>>(keys, h2, st, list);
    k_sort<<<dim3(1), dim3(1024), 0, stream>>>(keys, st, list, topk,
                                               (const float4*)boxes, boxk);
    k_mask<<<dim3(256), dim3(256), 0, stream>>>(boxk, mask);
    k_nms_out<<<dim3(1), dim3(256), 0, stream>>>(mask, topk, det, out);
}